// Round 2
// baseline (23438.336 us; speedup 1.0000x reference)
//
#include <hip/hip_runtime.h>
#include <hip/hip_bf16.h>
#include <math.h>

#define B_   128
#define S_   512
#define D_   384
#define H_   6
#define HD_  64
#define DIN_ 768
#define DFF_ 1536
#define NM_  6
#define NA_  2
#define EPS_ 1e-5f

// ---------------------------------------------------------------- embed
__global__ __launch_bounds__(128) void embed_kernel(const int* __restrict__ ids,
    const float* __restrict__ emb, const float* __restrict__ pos,
    float* __restrict__ x)
{
    int row = blockIdx.x;                 // b*S + s
    int id  = ids[row];
    int s   = row & (S_ - 1);             // S=512 pow2
    const float* e = emb + (size_t)id * D_;
    const float* p = pos + (size_t)s * D_;
    float* xr = x + (size_t)row * D_;
    for (int d = threadIdx.x; d < D_; d += 128) xr[d] = e[d] + p[d];
}

// ---------------------------------------------------------------- layernorm (optional fused residual add)
__global__ __launch_bounds__(128) void ln_kernel(const float* __restrict__ src,
    const float* __restrict__ res, const float* __restrict__ w,
    const float* __restrict__ bias, float* __restrict__ out)
{
    int row = blockIdx.x;
    const float* sr = src + (size_t)row * D_;
    int tid = threadIdx.x;
    float v[3];
    float s = 0.f, ss = 0.f;
    #pragma unroll
    for (int i = 0; i < 3; ++i) {
        int d = tid + i * 128;
        float t = sr[d];
        if (res) t += res[(size_t)row * D_ + d];
        v[i] = t; s += t; ss += t * t;
    }
    #pragma unroll
    for (int off = 32; off > 0; off >>= 1) {
        s  += __shfl_down(s, off);
        ss += __shfl_down(ss, off);
    }
    __shared__ float red[2][2];
    int wave = tid >> 6, lane = tid & 63;
    if (lane == 0) { red[wave][0] = s; red[wave][1] = ss; }
    __syncthreads();
    float S0 = red[0][0] + red[1][0];
    float SS = red[0][1] + red[1][1];
    float mu  = S0 * (1.f / D_);
    float var = SS * (1.f / D_) - mu * mu;
    float rs  = rsqrtf(var + EPS_);
    float* orow = out + (size_t)row * D_;
    #pragma unroll
    for (int i = 0; i < 3; ++i) {
        int d = tid + i * 128;
        orow[d] = (v[i] - mu) * rs * w[d] + bias[d];
    }
}

// ---------------------------------------------------------------- fp32 GEMM  C = act(A@W + bias) [+ R]
// A: MxK row-major, W: KxN row-major. M%128==0, N%128==0, K%16==0.
#define BM 128
#define BN 128
#define BK 16

__global__ __launch_bounds__(256) void gemm_kernel(
    const float* __restrict__ A, const float* __restrict__ W,
    const float* __restrict__ bias, const float* __restrict__ R,
    float* __restrict__ C, int M, int N, int K, int act, int hasres)
{
    __shared__ float As[BK][BM + 4];   // transposed: As[k][m]
    __shared__ float Bs[BK][BN + 4];
    const int tid = threadIdx.x;
    const int m0 = blockIdx.y * BM;
    const int n0 = blockIdx.x * BN;
    const int tx = tid & 15;           // col group
    const int ty = tid >> 4;           // row group
    float acc[8][8] = {};
    // staging assignments
    const int la_m = tid >> 1;          // 0..127
    const int la_k = (tid & 1) * 8;     // 0 / 8
    const int lb_k = tid >> 4;          // 0..15
    const int lb_n = (tid & 15) * 8;    // 0..120
    const float* Aptr = A + (size_t)(m0 + la_m) * K + la_k;
    const float* Wptr = W + (size_t)lb_k * N + n0 + lb_n;

    for (int k0 = 0; k0 < K; k0 += BK) {
        float4 a0 = *(const float4*)(Aptr + k0);
        float4 a1 = *(const float4*)(Aptr + k0 + 4);
        float4 b0 = *(const float4*)(Wptr + (size_t)k0 * N);
        float4 b1 = *(const float4*)(Wptr + (size_t)k0 * N + 4);
        As[la_k + 0][la_m] = a0.x;  As[la_k + 1][la_m] = a0.y;
        As[la_k + 2][la_m] = a0.z;  As[la_k + 3][la_m] = a0.w;
        As[la_k + 4][la_m] = a1.x;  As[la_k + 5][la_m] = a1.y;
        As[la_k + 6][la_m] = a1.z;  As[la_k + 7][la_m] = a1.w;
        *(float4*)&Bs[lb_k][lb_n]     = b0;
        *(float4*)&Bs[lb_k][lb_n + 4] = b1;
        __syncthreads();
        #pragma unroll
        for (int kk = 0; kk < BK; ++kk) {
            float4 av0 = *(const float4*)&As[kk][ty * 4];
            float4 av1 = *(const float4*)&As[kk][64 + ty * 4];
            float4 bv0 = *(const float4*)&Bs[kk][tx * 4];
            float4 bv1 = *(const float4*)&Bs[kk][64 + tx * 4];
            float a[8]  = {av0.x, av0.y, av0.z, av0.w, av1.x, av1.y, av1.z, av1.w};
            float bb[8] = {bv0.x, bv0.y, bv0.z, bv0.w, bv1.x, bv1.y, bv1.z, bv1.w};
            #pragma unroll
            for (int r = 0; r < 8; ++r)
                #pragma unroll
                for (int c = 0; c < 8; ++c)
                    acc[r][c] += a[r] * bb[c];
        }
        __syncthreads();
    }
    #pragma unroll
    for (int r = 0; r < 8; ++r) {
        int mrow = m0 + ((r < 4) ? (ty * 4 + r) : (64 + ty * 4 + (r - 4)));
        float* crow = C + (size_t)mrow * N;
        #pragma unroll
        for (int cg = 0; cg < 2; ++cg) {
            int ncol = n0 + ((cg == 0) ? tx * 4 : 64 + tx * 4);
            float4 v;
            float* vp = &v.x;
            #pragma unroll
            for (int c = 0; c < 4; ++c) {
                float t = acc[r][cg * 4 + c] + bias[ncol + c];
                if (act == 1) t = t / (1.f + __expf(-t));   // silu
                else if (act == 2) t = fmaxf(t, 0.f);       // relu
                vp[c] = t;
            }
            if (hasres) {
                const float* rrow = R + (size_t)mrow * N;
                float4 rv = *(const float4*)(rrow + ncol);
                v.x += rv.x; v.y += rv.y; v.z += rv.z; v.w += rv.w;
            }
            *(float4*)(crow + ncol) = v;
        }
    }
}

// ---------------------------------------------------------------- attention (two-pass, scores in LDS)
// qkv: (rows, 1152) = [q|k|v], heads of 64. o: (rows, 384). blockIdx.z = batch-in-chunk.
#define QT 16

__global__ __launch_bounds__(256) void attn_kernel(const float* __restrict__ qkv,
                                                   float* __restrict__ o)
{
    const int qt  = blockIdx.x;      // 0..S/QT-1
    const int h   = blockIdx.y;      // 0..5
    const int b   = blockIdx.z;      // batch element within chunk
    const int tid = threadIdx.x;
    __shared__ float Qt_[QT][68];
    __shared__ float KV[64][68];
    __shared__ float sc[QT][516];
    __shared__ float red[QT][17];

    const size_t baseRow = (size_t)b * S_;
    {   // load Q tile
        int r  = tid >> 4;
        int d0 = (tid & 15) * 4;
        const float* src = qkv + (baseRow + qt * QT + r) * 1152 + h * 64 + d0;
        *(float4*)&Qt_[r][d0] = *(const float4*)src;
    }
    const float scale = 0.125f;      // 1/sqrt(64)
    const int qi = tid & 15;
    const int m  = tid >> 4;         // 0..15

    // ---- scores = Q K^T * scale
    for (int kt = 0; kt < 8; ++kt) {
        __syncthreads();
        {   // load K tile (64 rows)
            int kr = tid >> 2;
            int c0 = (tid & 3) * 16;
            const float* src = qkv + (baseRow + kt * 64 + kr) * 1152 + 384 + h * 64 + c0;
            *(float4*)&KV[kr][c0]      = *(const float4*)(src);
            *(float4*)&KV[kr][c0 + 4]  = *(const float4*)(src + 4);
            *(float4*)&KV[kr][c0 + 8]  = *(const float4*)(src + 8);
            *(float4*)&KV[kr][c0 + 12] = *(const float4*)(src + 12);
        }
        __syncthreads();
        float acc4[4] = {0.f, 0.f, 0.f, 0.f};
        #pragma unroll
        for (int k4 = 0; k4 < 16; ++k4) {
            float4 qv = *(const float4*)&Qt_[qi][k4 * 4];
            #pragma unroll
            for (int j = 0; j < 4; ++j) {
                float4 kv = *(const float4*)&KV[m + 16 * j][k4 * 4];
                acc4[j] += qv.x * kv.x + qv.y * kv.y + qv.z * kv.z + qv.w * kv.w;
            }
        }
        #pragma unroll
        for (int j = 0; j < 4; ++j)
            sc[qi][kt * 64 + m + 16 * j] = acc4[j] * scale;
    }
    __syncthreads();

    // ---- softmax over 512 cols: row=qi, thread covers cols m*32..+31
    float mx = -1e30f;
    for (int c = 0; c < 32; ++c) mx = fmaxf(mx, sc[qi][m * 32 + c]);
    red[qi][m] = mx;
    __syncthreads();
    float rmax = -1e30f;
    #pragma unroll
    for (int j = 0; j < 16; ++j) rmax = fmaxf(rmax, red[qi][j]);
    float psum = 0.f;
    for (int c = 0; c < 32; ++c) {
        float e = __expf(sc[qi][m * 32 + c] - rmax);
        sc[qi][m * 32 + c] = e;
        psum += e;
    }
    __syncthreads();               // everyone done reading red (max)
    red[qi][m] = psum;
    __syncthreads();
    float rsum = 0.f;
    #pragma unroll
    for (int j = 0; j < 16; ++j) rsum += red[qi][j];
    float inv = 1.f / rsum;

    // ---- PV: thread computes o[qi][m*4 .. m*4+3]
    float oacc[4] = {0.f, 0.f, 0.f, 0.f};
    for (int kt = 0; kt < 8; ++kt) {
        __syncthreads();
        {   // load V tile
            int kr = tid >> 2;
            int c0 = (tid & 3) * 16;
            const float* src = qkv + (baseRow + kt * 64 + kr) * 1152 + 768 + h * 64 + c0;
            *(float4*)&KV[kr][c0]      = *(const float4*)(src);
            *(float4*)&KV[kr][c0 + 4]  = *(const float4*)(src + 4);
            *(float4*)&KV[kr][c0 + 8]  = *(const float4*)(src + 8);
            *(float4*)&KV[kr][c0 + 12] = *(const float4*)(src + 12);
        }
        __syncthreads();
        #pragma unroll 8
        for (int kj = 0; kj < 64; ++kj) {
            float s = sc[qi][kt * 64 + kj];
            float4 vv = *(const float4*)&KV[kj][m * 4];
            oacc[0] += s * vv.x; oacc[1] += s * vv.y;
            oacc[2] += s * vv.z; oacc[3] += s * vv.w;
        }
    }
    float4 ov = {oacc[0] * inv, oacc[1] * inv, oacc[2] * inv, oacc[3] * inv};
    *(float4*)(o + (baseRow + qt * QT + qi) * 384 + h * 64 + m * 4) = ov;
}

// ---------------------------------------------------------------- classifier head
__global__ __launch_bounds__(128) void head_kernel(const float* __restrict__ x,
    const float* __restrict__ w1, const float* __restrict__ b1,
    const float* __restrict__ w2, const float* __restrict__ b2,
    float* __restrict__ out)
{
    int b = blockIdx.x;
    int tid = threadIdx.x;
    __shared__ float cls[384];
    const float* xr = x + (size_t)b * S_ * 384;   // s=0 row
    for (int d = tid; d < 384; d += 128) cls[d] = xr[d];
    __syncthreads();
    float hacc = b1[tid];
    for (int k = 0; k < 384; ++k) hacc += cls[k] * w1[k * 128 + tid];
    hacc = fmaxf(hacc, 0.f);
    float p = hacc * w2[tid];
    #pragma unroll
    for (int off = 32; off > 0; off >>= 1) p += __shfl_down(p, off);
    __shared__ float r2[2];
    if ((tid & 63) == 0) r2[tid >> 6] = p;
    __syncthreads();
    if (tid == 0) out[b] = r2[0] + r2[1] + b2[0];
}

// ---------------------------------------------------------------- launch
// Workspace layout (floats):
//   bufX : M*384          persistent residual stream (100.7 MB)
//   t0   : MC*384         ln out / attn-proj out
//   t1   : MC*1536        MLP mid (768) / qkv (1152) / FF mid (1536)
//   t2   : MC*384         attention output
// total = M*384 + MC*2304 floats = 176 MB  (MC = M/8 = 8192 rows = 16 batches)
extern "C" void kernel_launch(void* const* d_in, const int* in_sizes, int n_in,
                              void* d_out, int out_size, void* d_ws, size_t ws_size,
                              hipStream_t stream)
{
    const int*   ids     = (const int*)d_in[0];
    const float* emb     = (const float*)d_in[1];
    const float* pos     = (const float*)d_in[2];
    const float* m_ln_w  = (const float*)d_in[3];
    const float* m_ln_b  = (const float*)d_in[4];
    const float* m_W1    = (const float*)d_in[5];
    const float* m_b1    = (const float*)d_in[6];
    const float* m_W2    = (const float*)d_in[7];
    const float* m_b2    = (const float*)d_in[8];
    const float* a_qkv_w = (const float*)d_in[9];
    const float* a_qkv_b = (const float*)d_in[10];
    const float* a_out_w = (const float*)d_in[11];
    const float* a_out_b = (const float*)d_in[12];
    const float* a_ln1_w = (const float*)d_in[13];
    const float* a_ln1_b = (const float*)d_in[14];
    const float* a_ln2_w = (const float*)d_in[15];
    const float* a_ln2_b = (const float*)d_in[16];
    const float* a_ff_w1 = (const float*)d_in[17];
    const float* a_ff_b1 = (const float*)d_in[18];
    const float* a_ff_w2 = (const float*)d_in[19];
    const float* a_ff_b2 = (const float*)d_in[20];
    const float* fn_w    = (const float*)d_in[21];
    const float* fn_b    = (const float*)d_in[22];
    const float* h_w1    = (const float*)d_in[23];
    const float* h_b1    = (const float*)d_in[24];
    const float* h_w2    = (const float*)d_in[25];
    const float* h_b2    = (const float*)d_in[26];
    float* out = (float*)d_out;

    const size_t M  = (size_t)B_ * S_;     // 65536
    const int    NC = 8;                   // chunks
    const size_t MC = M / NC;              // 8192 rows = 16 batch elements
    const int    BC = (int)(MC / S_);      // 16 batches per chunk

    float* bufX = (float*)d_ws;            // M*384
    float* t0   = bufX + M * 384;          // MC*384
    float* t1   = t0 + MC * 384;           // MC*1536
    float* t2   = t1 + MC * 1536;          // MC*384

    embed_kernel<<<(int)M, 128, 0, stream>>>(ids, emb, pos, bufX);

    for (int i = 0; i < NM_; ++i) {
        for (int c = 0; c < NC; ++c) {
            float* xc = bufX + (size_t)c * MC * 384;
            ln_kernel<<<(int)MC, 128, 0, stream>>>(xc, nullptr, m_ln_w + i * D_, m_ln_b + i * D_, t0);
            gemm_kernel<<<dim3(DIN_ / BN, (int)(MC / BM)), 256, 0, stream>>>(
                t0, m_W1 + (size_t)i * D_ * DIN_, m_b1 + i * DIN_, nullptr, t1,
                (int)MC, DIN_, D_, 1, 0);
            gemm_kernel<<<dim3(D_ / BN, (int)(MC / BM)), 256, 0, stream>>>(
                t1, m_W2 + (size_t)i * DIN_ * D_, m_b2 + i * D_, xc, xc,
                (int)MC, D_, DIN_, 0, 1);
        }
    }
    for (int i = 0; i < NA_; ++i) {
        for (int c = 0; c < NC; ++c) {
            float* xc = bufX + (size_t)c * MC * 384;
            gemm_kernel<<<dim3(1152 / BN, (int)(MC / BM)), 256, 0, stream>>>(
                xc, a_qkv_w + (size_t)i * D_ * 1152, a_qkv_b + i * 1152, nullptr, t1,
                (int)MC, 1152, D_, 0, 0);
            attn_kernel<<<dim3(S_ / QT, H_, BC), 256, 0, stream>>>(t1, t2);
            gemm_kernel<<<dim3(D_ / BN, (int)(MC / BM)), 256, 0, stream>>>(
                t2, a_out_w + (size_t)i * D_ * D_, a_out_b + i * D_, nullptr, t0,
                (int)MC, D_, D_, 0, 0);
            ln_kernel<<<(int)MC, 128, 0, stream>>>(xc, t0, a_ln1_w + i * D_, a_ln1_b + i * D_, xc);
            gemm_kernel<<<dim3(DFF_ / BN, (int)(MC / BM)), 256, 0, stream>>>(
                xc, a_ff_w1 + (size_t)i * D_ * DFF_, a_ff_b1 + i * DFF_, nullptr, t1,
                (int)MC, DFF_, D_, 2, 0);
            gemm_kernel<<<dim3(D_ / BN, (int)(MC / BM)), 256, 0, stream>>>(
                t1, a_ff_w2 + (size_t)i * DFF_ * D_, a_ff_b2 + i * D_, nullptr, t0,
                (int)MC, D_, DFF_, 0, 0);
            ln_kernel<<<(int)MC, 128, 0, stream>>>(xc, t0, a_ln2_w + i * D_, a_ln2_b + i * D_, xc);
        }
    }
    ln_kernel<<<(int)M, 128, 0, stream>>>(bufX, nullptr, fn_w, fn_b, bufX);
    head_kernel<<<B_, 128, 0, stream>>>(bufX, h_w1, h_b1, h_w2, h_b2, out);
}

// Round 3
// 10525.430 us; speedup vs baseline: 2.2268x; 2.2268x over previous
//
#include <hip/hip_runtime.h>
#include <hip/hip_bf16.h>
#include <math.h>

#define B_   128
#define S_   512
#define D_   384
#define H_   6
#define HD_  64
#define DIN_ 768
#define DFF_ 1536
#define NM_  6
#define NA_  2
#define EPS_ 1e-5f

typedef __hip_bfloat16 bf16;
typedef __attribute__((ext_vector_type(8))) short short8;
typedef __attribute__((ext_vector_type(4))) float f32x4;

__device__ __forceinline__ float bf2f(unsigned short u) {
    union { unsigned int i; float f; } c; c.i = ((unsigned int)u) << 16; return c.f;
}

__device__ __forceinline__ void async16(const void* g, void* l) {
    __builtin_amdgcn_global_load_lds((const __attribute__((address_space(1))) void*)g,
                                     (__attribute__((address_space(3))) void*)l, 16, 0, 0);
}

// ---------------------------------------------------------------- embed (fp32 out)
__global__ __launch_bounds__(128) void embed_kernel(const int* __restrict__ ids,
    const float* __restrict__ emb, const float* __restrict__ pos,
    float* __restrict__ x)
{
    int row = blockIdx.x;
    int id  = ids[row];
    int s   = row & (S_ - 1);
    const float* e = emb + (size_t)id * D_;
    const float* p = pos + (size_t)s * D_;
    float* xr = x + (size_t)row * D_;
    for (int d = threadIdx.x; d < D_; d += 128) xr[d] = e[d] + p[d];
}

// ---------------------------------------------------------------- layernorm: optional residual, dual dtype out
__global__ __launch_bounds__(128) void ln_kernel(const float* __restrict__ src,
    const float* __restrict__ res, const float* __restrict__ w,
    const float* __restrict__ bias, float* __restrict__ outf, bf16* __restrict__ outb)
{
    int row = blockIdx.x;
    const float* sr = src + (size_t)row * D_;
    int tid = threadIdx.x;
    float v[3];
    float s = 0.f, ss = 0.f;
    #pragma unroll
    for (int i = 0; i < 3; ++i) {
        int d = tid + i * 128;
        float t = sr[d];
        if (res) t += res[(size_t)row * D_ + d];
        v[i] = t; s += t; ss += t * t;
    }
    #pragma unroll
    for (int off = 32; off > 0; off >>= 1) {
        s  += __shfl_down(s, off);
        ss += __shfl_down(ss, off);
    }
    __shared__ float red[2][2];
    int wave = tid >> 6, lane = tid & 63;
    if (lane == 0) { red[wave][0] = s; red[wave][1] = ss; }
    __syncthreads();
    float S0 = red[0][0] + red[1][0];
    float SS = red[0][1] + red[1][1];
    float mu  = S0 * (1.f / D_);
    float var = SS * (1.f / D_) - mu * mu;
    float rs  = rsqrtf(var + EPS_);
    #pragma unroll
    for (int i = 0; i < 3; ++i) {
        int d = tid + i * 128;
        float o = (v[i] - mu) * rs * w[d] + bias[d];
        if (outf) outf[(size_t)row * D_ + d] = o;
        if (outb) outb[(size_t)row * D_ + d] = __float2bfloat16(o);
    }
}

// ---------------------------------------------------------------- final LN on CLS rows only
__global__ __launch_bounds__(128) void ln_cls_kernel(const float* __restrict__ x,
    const float* __restrict__ w, const float* __restrict__ bias, float* __restrict__ cls)
{
    int b = blockIdx.x;
    const float* sr = x + (size_t)b * S_ * D_;
    int tid = threadIdx.x;
    float v[3];
    float s = 0.f, ss = 0.f;
    #pragma unroll
    for (int i = 0; i < 3; ++i) {
        int d = tid + i * 128;
        float t = sr[d];
        v[i] = t; s += t; ss += t * t;
    }
    #pragma unroll
    for (int off = 32; off > 0; off >>= 1) {
        s  += __shfl_down(s, off);
        ss += __shfl_down(ss, off);
    }
    __shared__ float red[2][2];
    int wave = tid >> 6, lane = tid & 63;
    if (lane == 0) { red[wave][0] = s; red[wave][1] = ss; }
    __syncthreads();
    float S0 = red[0][0] + red[1][0];
    float SS = red[0][1] + red[1][1];
    float mu  = S0 * (1.f / D_);
    float var = SS * (1.f / D_) - mu * mu;
    float rs  = rsqrtf(var + EPS_);
    #pragma unroll
    for (int i = 0; i < 3; ++i) {
        int d = tid + i * 128;
        cls[(size_t)b * D_ + d] = (v[i] - mu) * rs * w[d] + bias[d];
    }
}

// ---------------------------------------------------------------- fp32 -> bf16 cvt
__global__ __launch_bounds__(256) void cvt_kernel(const float* __restrict__ x,
                                                  bf16* __restrict__ xb)
{
    int i = (blockIdx.x * 256 + threadIdx.x) * 4;
    float4 v = *(const float4*)(x + i);
    bf16* o = xb + i;
    o[0] = __float2bfloat16(v.x); o[1] = __float2bfloat16(v.y);
    o[2] = __float2bfloat16(v.z); o[3] = __float2bfloat16(v.w);
}

// ---------------------------------------------------------------- weight transpose+cvt: W (KxN fp32) -> Wt (NxK bf16)
__global__ __launch_bounds__(256) void wcvt_kernel(const float* __restrict__ W,
    bf16* __restrict__ Wt, int K, int N)
{
    __shared__ float tile[32][33];
    int tid = threadIdx.x;
    int tx = tid & 31, ty = tid >> 5;       // ty 0..7
    int n0 = blockIdx.x * 32, k0 = blockIdx.y * 32;
    #pragma unroll
    for (int i = 0; i < 4; ++i)
        tile[ty + i * 8][tx] = W[(size_t)(k0 + ty + i * 8) * N + n0 + tx];
    __syncthreads();
    #pragma unroll
    for (int i = 0; i < 4; ++i)
        Wt[(size_t)(n0 + ty + i * 8) * K + k0 + tx] = __float2bfloat16(tile[tx][ty + i * 8]);
}

// ---------------------------------------------------------------- bf16 MFMA GEMM
// A: McxK bf16 row-major.  Bt: NxK bf16 row-major (= W^T).  C = act(A@W + bias) [+R]
// out: Cf (fp32) and/or Cb (bf16).  Mc%128==0, N%128==0, K%32==0.
__global__ __launch_bounds__(256) void gemm_bf16(
    const bf16* __restrict__ A, const bf16* __restrict__ Bt,
    const float* __restrict__ bias, const float* __restrict__ R,
    float* __restrict__ Cf, bf16* __restrict__ Cb,
    int N, int K, int act)
{
    __shared__ __align__(16) short As[2][4096];   // [plane][128 rows x 32 k]
    __shared__ __align__(16) short Bs[2][4096];
    const int tid  = threadIdx.x;
    const int wave = tid >> 6, lane = tid & 63;
    const int m0 = blockIdx.y * 128;
    const int n0 = blockIdx.x * 128;
    const int lr = lane & 15, lk = lane >> 4;
    const int wm = wave >> 1, wn = wave & 1;

    const bf16* Ab = A  + (size_t)m0 * K;
    const bf16* Bb = Bt + (size_t)n0 * K;

    // staging lane mapping (linear LDS dest, pre-swizzled global source)
    const int st_row  = (wave * 2) * 16 + (lane >> 2);     // chunk j adds 16
    const int st_col0 = (lane & 3);

    f32x4 acc[4][4];
    #pragma unroll
    for (int i = 0; i < 4; ++i)
        #pragma unroll
        for (int j = 0; j < 4; ++j)
            acc[i][j] = (f32x4){0.f, 0.f, 0.f, 0.f};

    const int KT = K >> 5;

    // prologue stage: plane 0, k0 = 0
    #pragma unroll
    for (int j = 0; j < 2; ++j) {
        int row = st_row + j * 16;
        int ks  = st_col0 ^ (row & 3);
        int chunk = wave * 2 + j;
        async16(Ab + (size_t)row * K + ks * 8, &As[0][chunk * 512]);
        async16(Bb + (size_t)row * K + ks * 8, &Bs[0][chunk * 512]);
    }

    for (int kt = 0; kt < KT; ++kt) {
        const int cur = kt & 1;
        __syncthreads();    // drains this wave's global_load_lds; all waves' cur-plane data ready
        if (kt + 1 < KT) {
            const int k0 = (kt + 1) << 5;
            #pragma unroll
            for (int j = 0; j < 2; ++j) {
                int row = st_row + j * 16;
                int ks  = st_col0 ^ (row & 3);
                int chunk = wave * 2 + j;
                async16(Ab + (size_t)row * K + k0 + ks * 8, &As[cur ^ 1][chunk * 512]);
                async16(Bb + (size_t)row * K + k0 + ks * 8, &Bs[cur ^ 1][chunk * 512]);
            }
        }
        short8 af[4], bfr[4];
        #pragma unroll
        for (int i = 0; i < 4; ++i) {
            int ra = wm * 64 + i * 16 + lr;
            af[i]  = *(const short8*)&As[cur][ra * 32 + ((lk ^ (ra & 3)) << 3)];
            int rb = wn * 64 + i * 16 + lr;
            bfr[i] = *(const short8*)&Bs[cur][rb * 32 + ((lk ^ (rb & 3)) << 3)];
        }
        #pragma unroll
        for (int mi = 0; mi < 4; ++mi)
            #pragma unroll
            for (int ni = 0; ni < 4; ++ni)
                acc[mi][ni] = __builtin_amdgcn_mfma_f32_16x16x32_bf16(af[mi], bfr[ni], acc[mi][ni], 0, 0, 0);
    }

    // epilogue
    #pragma unroll
    for (int mi = 0; mi < 4; ++mi) {
        #pragma unroll
        for (int ni = 0; ni < 4; ++ni) {
            int col = n0 + wn * 64 + ni * 16 + lr;
            float bv = bias[col];
            #pragma unroll
            for (int j = 0; j < 4; ++j) {
                int row = m0 + wm * 64 + mi * 16 + lk * 4 + j;
                float t = acc[mi][ni][j] + bv;
                if (act == 1)      t = t / (1.f + __expf(-t));
                else if (act == 2) t = fmaxf(t, 0.f);
                size_t idx = (size_t)row * N + col;
                if (R)  t += R[idx];
                if (Cf) Cf[idx] = t;
                if (Cb) Cb[idx] = __float2bfloat16(t);
            }
        }
    }
}

// ---------------------------------------------------------------- attention (fp32 math, bf16 I/O)
#define QT 16

__global__ __launch_bounds__(256) void attn_kernel(const bf16* __restrict__ qkv,
                                                   bf16* __restrict__ o)
{
    const int qt  = blockIdx.x;
    const int h   = blockIdx.y;
    const int b   = blockIdx.z;
    const int tid = threadIdx.x;
    __shared__ float Qt_[QT][68];
    __shared__ float KV[64][68];
    __shared__ float sc[QT][516];
    __shared__ float red[QT][17];

    const size_t baseRow = (size_t)b * S_;
    {   // Q tile
        int r  = tid >> 4;
        int d0 = (tid & 15) * 4;
        const bf16* src = qkv + (baseRow + qt * QT + r) * 1152 + h * 64 + d0;
        ushort4 u = *(const ushort4*)src;
        Qt_[r][d0 + 0] = bf2f(u.x); Qt_[r][d0 + 1] = bf2f(u.y);
        Qt_[r][d0 + 2] = bf2f(u.z); Qt_[r][d0 + 3] = bf2f(u.w);
    }
    const float scale = 0.125f;
    const int qi = tid & 15;
    const int m  = tid >> 4;

    for (int kt = 0; kt < 8; ++kt) {
        __syncthreads();
        {   // K tile
            int kr = tid >> 2;
            int c0 = (tid & 3) * 16;
            const bf16* src = qkv + (baseRow + kt * 64 + kr) * 1152 + 384 + h * 64 + c0;
            short8 v0 = *(const short8*)(src);
            short8 v1 = *(const short8*)(src + 8);
            #pragma unroll
            for (int j = 0; j < 8; ++j) {
                KV[kr][c0 + j]     = bf2f((unsigned short)v0[j]);
                KV[kr][c0 + 8 + j] = bf2f((unsigned short)v1[j]);
            }
        }
        __syncthreads();
        float acc4[4] = {0.f, 0.f, 0.f, 0.f};
        #pragma unroll
        for (int k4 = 0; k4 < 16; ++k4) {
            float4 qv = *(const float4*)&Qt_[qi][k4 * 4];
            #pragma unroll
            for (int j = 0; j < 4; ++j) {
                float4 kv = *(const float4*)&KV[m + 16 * j][k4 * 4];
                acc4[j] += qv.x * kv.x + qv.y * kv.y + qv.z * kv.z + qv.w * kv.w;
            }
        }
        #pragma unroll
        for (int j = 0; j < 4; ++j)
            sc[qi][kt * 64 + m + 16 * j] = acc4[j] * scale;
    }
    __syncthreads();

    float mx = -1e30f;
    for (int c = 0; c < 32; ++c) mx = fmaxf(mx, sc[qi][m * 32 + c]);
    red[qi][m] = mx;
    __syncthreads();
    float rmax = -1e30f;
    #pragma unroll
    for (int j = 0; j < 16; ++j) rmax = fmaxf(rmax, red[qi][j]);
    float psum = 0.f;
    for (int c = 0; c < 32; ++c) {
        float e = __expf(sc[qi][m * 32 + c] - rmax);
        sc[qi][m * 32 + c] = e;
        psum += e;
    }
    __syncthreads();
    red[qi][m] = psum;
    __syncthreads();
    float rsum = 0.f;
    #pragma unroll
    for (int j = 0; j < 16; ++j) rsum += red[qi][j];
    float inv = 1.f / rsum;

    float oacc[4] = {0.f, 0.f, 0.f, 0.f};
    for (int kt = 0; kt < 8; ++kt) {
        __syncthreads();
        {   // V tile
            int kr = tid >> 2;
            int c0 = (tid & 3) * 16;
            const bf16* src = qkv + (baseRow + kt * 64 + kr) * 1152 + 768 + h * 64 + c0;
            short8 v0 = *(const short8*)(src);
            short8 v1 = *(const short8*)(src + 8);
            #pragma unroll
            for (int j = 0; j < 8; ++j) {
                KV[kr][c0 + j]     = bf2f((unsigned short)v0[j]);
                KV[kr][c0 + 8 + j] = bf2f((unsigned short)v1[j]);
            }
        }
        __syncthreads();
        #pragma unroll 8
        for (int kj = 0; kj < 64; ++kj) {
            float s = sc[qi][kt * 64 + kj];
            float4 vv = *(const float4*)&KV[kj][m * 4];
            oacc[0] += s * vv.x; oacc[1] += s * vv.y;
            oacc[2] += s * vv.z; oacc[3] += s * vv.w;
        }
    }
    union { ushort4 u; unsigned short s[4]; } pk;
    #pragma unroll
    for (int j = 0; j < 4; ++j) {
        bf16 t = __float2bfloat16(oacc[j] * inv);
        pk.s[j] = *(unsigned short*)&t;
    }
    *(ushort4*)(o + (baseRow + qt * QT + qi) * 384 + h * 64 + m * 4) = pk.u;
}

// ---------------------------------------------------------------- classifier head (reads 128x384 fp32 cls)
__global__ __launch_bounds__(128) void head_kernel(const float* __restrict__ cls,
    const float* __restrict__ w1, const float* __restrict__ b1,
    const float* __restrict__ w2, const float* __restrict__ b2,
    float* __restrict__ out)
{
    int b = blockIdx.x;
    int tid = threadIdx.x;
    __shared__ float c[384];
    const float* xr = cls + (size_t)b * 384;
    for (int d = tid; d < 384; d += 128) c[d] = xr[d];
    __syncthreads();
    float hacc = b1[tid];
    for (int k = 0; k < 384; ++k) hacc += c[k] * w1[k * 128 + tid];
    hacc = fmaxf(hacc, 0.f);
    float p = hacc * w2[tid];
    #pragma unroll
    for (int off = 32; off > 0; off >>= 1) p += __shfl_down(p, off);
    __shared__ float r2[2];
    if ((tid & 63) == 0) r2[tid >> 6] = p;
    __syncthreads();
    if (tid == 0) out[b] = r2[0] + r2[1] + b2[0];
}

// ---------------------------------------------------------------- launch
extern "C" void kernel_launch(void* const* d_in, const int* in_sizes, int n_in,
                              void* d_out, int out_size, void* d_ws, size_t ws_size,
                              hipStream_t stream)
{
    const int*   ids     = (const int*)d_in[0];
    const float* emb     = (const float*)d_in[1];
    const float* pos     = (const float*)d_in[2];
    const float* m_ln_w  = (const float*)d_in[3];
    const float* m_ln_b  = (const float*)d_in[4];
    const float* m_W1    = (const float*)d_in[5];
    const float* m_b1    = (const float*)d_in[6];
    const float* m_W2    = (const float*)d_in[7];
    const float* m_b2    = (const float*)d_in[8];
    const float* a_qkv_w = (const float*)d_in[9];
    const float* a_qkv_b = (const float*)d_in[10];
    const float* a_out_w = (const float*)d_in[11];
    const float* a_out_b = (const float*)d_in[12];
    const float* a_ln1_w = (const float*)d_in[13];
    const float* a_ln1_b = (const float*)d_in[14];
    const float* a_ln2_w = (const float*)d_in[15];
    const float* a_ln2_b = (const float*)d_in[16];
    const float* a_ff_w1 = (const float*)d_in[17];
    const float* a_ff_b1 = (const float*)d_in[18];
    const float* a_ff_w2 = (const float*)d_in[19];
    const float* a_ff_b2 = (const float*)d_in[20];
    const float* fn_w    = (const float*)d_in[21];
    const float* fn_b    = (const float*)d_in[22];
    const float* h_w1    = (const float*)d_in[23];
    const float* h_b1    = (const float*)d_in[24];
    const float* h_w2    = (const float*)d_in[25];
    const float* h_b2    = (const float*)d_in[26];
    float* out = (float*)d_out;

    const size_t M  = (size_t)B_ * S_;     // 65536
    const int    NC = 8;
    const size_t MC = M / NC;              // 8192 rows
    const int    BC = (int)(MC / S_);      // 16

    // workspace: 158 MB total
    char* w = (char*)d_ws;
    float* x    = (float*)w;                w += M  * 384 * 4;   // residual stream fp32
    float* t0   = (float*)w;                w += MC * 384 * 4;   // pre-residual gemm out fp32
    bf16*  xcb  = (bf16*)w;                 w += MC * 384 * 2;   // bf16 GEMM A input
    bf16*  midb = (bf16*)w;                 w += MC * 1536 * 2;  // mid / qkv bf16
    bf16*  t2b  = (bf16*)w;                 w += MC * 384 * 2;   // attn out bf16
    bf16*  Wt   = (bf16*)w;                                      // transposed bf16 weights

    bf16* mW1t = Wt;                        // 6 x (768x384)
    bf16* mW2t = mW1t + 6 * 768 * 384;      // 6 x (384x768)
    bf16* qkvt = mW2t + 6 * 384 * 768;      // 2 x (1152x384)
    bf16* outt = qkvt + 2 * 1152 * 384;     // 2 x (384x384)
    bf16* ff1t = outt + 2 * 384 * 384;      // 2 x (1536x384)
    bf16* ff2t = ff1t + 2 * 1536 * 384;     // 2 x (384x1536)

    // ---- weight conversion (every launch; ~30us)
    for (int i = 0; i < NM_; ++i) {
        wcvt_kernel<<<dim3(DIN_ / 32, D_ / 32), 256, 0, stream>>>(m_W1 + (size_t)i * D_ * DIN_, mW1t + (size_t)i * DIN_ * D_, D_, DIN_);
        wcvt_kernel<<<dim3(D_ / 32, DIN_ / 32), 256, 0, stream>>>(m_W2 + (size_t)i * DIN_ * D_, mW2t + (size_t)i * D_ * DIN_, DIN_, D_);
    }
    for (int i = 0; i < NA_; ++i) {
        wcvt_kernel<<<dim3(1152 / 32, D_ / 32), 256, 0, stream>>>(a_qkv_w + (size_t)i * D_ * 1152, qkvt + (size_t)i * 1152 * D_, D_, 1152);
        wcvt_kernel<<<dim3(D_ / 32, D_ / 32), 256, 0, stream>>>(a_out_w + (size_t)i * D_ * D_, outt + (size_t)i * D_ * D_, D_, D_);
        wcvt_kernel<<<dim3(DFF_ / 32, D_ / 32), 256, 0, stream>>>(a_ff_w1 + (size_t)i * D_ * DFF_, ff1t + (size_t)i * DFF_ * D_, D_, DFF_);
        wcvt_kernel<<<dim3(D_ / 32, DFF_ / 32), 256, 0, stream>>>(a_ff_w2 + (size_t)i * DFF_ * D_, ff2t + (size_t)i * D_ * DFF_, DFF_, D_);
    }

    embed_kernel<<<(int)M, 128, 0, stream>>>(ids, emb, pos, x);

    const int GM = (int)(MC / 128);        // 64

    for (int i = 0; i < NM_; ++i) {
        for (int c = 0; c < NC; ++c) {
            float* xc = x + (size_t)c * MC * 384;
            ln_kernel<<<(int)MC, 128, 0, stream>>>(xc, nullptr, m_ln_w + i * D_, m_ln_b + i * D_, nullptr, xcb);
            gemm_bf16<<<dim3(DIN_ / 128, GM), 256, 0, stream>>>(
                xcb, mW1t + (size_t)i * DIN_ * D_, m_b1 + i * DIN_, nullptr, nullptr, midb, DIN_, D_, 1);
            gemm_bf16<<<dim3(D_ / 128, GM), 256, 0, stream>>>(
                midb, mW2t + (size_t)i * D_ * DIN_, m_b2 + i * D_, xc, xc, nullptr, D_, DIN_, 0);
        }
    }
    for (int i = 0; i < NA_; ++i) {
        for (int c = 0; c < NC; ++c) {
            float* xc = x + (size_t)c * MC * 384;
            cvt_kernel<<<(int)(MC * 384 / 1024), 256, 0, stream>>>(xc, xcb);
            gemm_bf16<<<dim3(1152 / 128, GM), 256, 0, stream>>>(
                xcb, qkvt + (size_t)i * 1152 * D_, a_qkv_b + i * 1152, nullptr, nullptr, midb, 1152, D_, 0);
            attn_kernel<<<dim3(S_ / QT, H_, BC), 256, 0, stream>>>(midb, t2b);
            gemm_bf16<<<dim3(D_ / 128, GM), 256, 0, stream>>>(
                t2b, outt + (size_t)i * D_ * D_, a_out_b + i * D_, nullptr, t0, nullptr, D_, D_, 0);
            ln_kernel<<<(int)MC, 128, 0, stream>>>(xc, t0, a_ln1_w + i * D_, a_ln1_b + i * D_, xc, xcb);
            gemm_bf16<<<dim3(DFF_ / 128, GM), 256, 0, stream>>>(
                xcb, ff1t + (size_t)i * DFF_ * D_, a_ff_b1 + i * DFF_, nullptr, nullptr, midb, DFF_, D_, 2);
            gemm_bf16<<<dim3(D_ / 128, GM), 256, 0, stream>>>(
                midb, ff2t + (size_t)i * D_ * DFF_, a_ff_b2 + i * D_, nullptr, t0, nullptr, D_, DFF_, 0);
            ln_kernel<<<(int)MC, 128, 0, stream>>>(xc, t0, a_ln2_w + i * D_, a_ln2_b + i * D_, xc, nullptr);
        }
    }
    ln_cls_kernel<<<B_, 128, 0, stream>>>(x, fn_w, fn_b, t0);
    head_kernel<<<B_, 128, 0, stream>>>(t0, h_w1, h_b1, h_w2, h_b2, out);
}

// Round 5
// 4074.968 us; speedup vs baseline: 5.7518x; 2.5829x over previous
//
#include <hip/hip_runtime.h>
#include <hip/hip_bf16.h>
#include <math.h>

#define B_   128
#define S_   512
#define D_   384
#define H_   6
#define HD_  64
#define DIN_ 768
#define DFF_ 1536
#define NM_  6
#define NA_  2
#define EPS_ 1e-5f

typedef __hip_bfloat16 bf16;
typedef __attribute__((ext_vector_type(8))) short short8;
typedef __attribute__((ext_vector_type(4))) float f32x4;

__device__ __forceinline__ float bf2f(unsigned short u) {
    union { unsigned int i; float f; } c; c.i = ((unsigned int)u) << 16; return c.f;
}

__device__ __forceinline__ void async16(const void* g, void* l) {
    __builtin_amdgcn_global_load_lds((const __attribute__((address_space(1))) void*)g,
                                     (__attribute__((address_space(3))) void*)l, 16, 0, 0);
}

// ---------------------------------------------------------------- embed (fp32 out)
__global__ __launch_bounds__(128) void embed_kernel(const int* __restrict__ ids,
    const float* __restrict__ emb, const float* __restrict__ pos,
    float* __restrict__ x)
{
    int row = blockIdx.x;
    int id  = ids[row];
    int s   = row & (S_ - 1);
    const float* e = emb + (size_t)id * D_;
    const float* p = pos + (size_t)s * D_;
    float* xr = x + (size_t)row * D_;
    for (int d = threadIdx.x; d < D_; d += 128) xr[d] = e[d] + p[d];
}

// ---------------------------------------------------------------- layernorm: optional residual, dual dtype out
__global__ __launch_bounds__(128) void ln_kernel(const float* __restrict__ src,
    const float* __restrict__ res, const float* __restrict__ w,
    const float* __restrict__ bias, float* __restrict__ outf, bf16* __restrict__ outb)
{
    int row = blockIdx.x;
    const float* sr = src + (size_t)row * D_;
    int tid = threadIdx.x;
    float v[3];
    float s = 0.f, ss = 0.f;
    #pragma unroll
    for (int i = 0; i < 3; ++i) {
        int d = tid + i * 128;
        float t = sr[d];
        if (res) t += res[(size_t)row * D_ + d];
        v[i] = t; s += t; ss += t * t;
    }
    #pragma unroll
    for (int off = 32; off > 0; off >>= 1) {
        s  += __shfl_down(s, off);
        ss += __shfl_down(ss, off);
    }
    __shared__ float red[2][2];
    int wave = tid >> 6, lane = tid & 63;
    if (lane == 0) { red[wave][0] = s; red[wave][1] = ss; }
    __syncthreads();
    float S0 = red[0][0] + red[1][0];
    float SS = red[0][1] + red[1][1];
    float mu  = S0 * (1.f / D_);
    float var = SS * (1.f / D_) - mu * mu;
    float rs  = rsqrtf(var + EPS_);
    #pragma unroll
    for (int i = 0; i < 3; ++i) {
        int d = tid + i * 128;
        float o = (v[i] - mu) * rs * w[d] + bias[d];
        if (outf) outf[(size_t)row * D_ + d] = o;
        if (outb) outb[(size_t)row * D_ + d] = __float2bfloat16(o);
    }
}

// ---------------------------------------------------------------- final LN on CLS rows only
__global__ __launch_bounds__(128) void ln_cls_kernel(const float* __restrict__ x,
    const float* __restrict__ w, const float* __restrict__ bias, float* __restrict__ cls)
{
    int b = blockIdx.x;
    const float* sr = x + (size_t)b * S_ * D_;
    int tid = threadIdx.x;
    float v[3];
    float s = 0.f, ss = 0.f;
    #pragma unroll
    for (int i = 0; i < 3; ++i) {
        int d = tid + i * 128;
        float t = sr[d];
        v[i] = t; s += t; ss += t * t;
    }
    #pragma unroll
    for (int off = 32; off > 0; off >>= 1) {
        s  += __shfl_down(s, off);
        ss += __shfl_down(ss, off);
    }
    __shared__ float red[2][2];
    int wave = tid >> 6, lane = tid & 63;
    if (lane == 0) { red[wave][0] = s; red[wave][1] = ss; }
    __syncthreads();
    float S0 = red[0][0] + red[1][0];
    float SS = red[0][1] + red[1][1];
    float mu  = S0 * (1.f / D_);
    float var = SS * (1.f / D_) - mu * mu;
    float rs  = rsqrtf(var + EPS_);
    #pragma unroll
    for (int i = 0; i < 3; ++i) {
        int d = tid + i * 128;
        cls[(size_t)b * D_ + d] = (v[i] - mu) * rs * w[d] + bias[d];
    }
}

// ---------------------------------------------------------------- fp32 -> bf16 cvt
__global__ __launch_bounds__(256) void cvt_kernel(const float* __restrict__ x,
                                                  bf16* __restrict__ xb)
{
    int i = (blockIdx.x * 256 + threadIdx.x) * 4;
    float4 v = *(const float4*)(x + i);
    bf16* o = xb + i;
    o[0] = __float2bfloat16(v.x); o[1] = __float2bfloat16(v.y);
    o[2] = __float2bfloat16(v.z); o[3] = __float2bfloat16(v.w);
}

// ---------------------------------------------------------------- weight transpose+cvt: W (KxN fp32) -> Wt (NxK bf16)
__global__ __launch_bounds__(256) void wcvt_kernel(const float* __restrict__ W,
    bf16* __restrict__ Wt, int K, int N)
{
    __shared__ float tile[32][33];
    int tid = threadIdx.x;
    int tx = tid & 31, ty = tid >> 5;
    int n0 = blockIdx.x * 32, k0 = blockIdx.y * 32;
    #pragma unroll
    for (int i = 0; i < 4; ++i)
        tile[ty + i * 8][tx] = W[(size_t)(k0 + ty + i * 8) * N + n0 + tx];
    __syncthreads();
    #pragma unroll
    for (int i = 0; i < 4; ++i)
        Wt[(size_t)(n0 + ty + i * 8) * K + k0 + tx] = __float2bfloat16(tile[tx][ty + i * 8]);
}

// ---------------------------------------------------------------- bf16 MFMA GEMM
// A: McxK bf16 row-major.  Bt: NxK bf16 row-major (= W^T).  C = act(A@W + bias) [+R]
__global__ __launch_bounds__(256) void gemm_bf16(
    const bf16* __restrict__ A, const bf16* __restrict__ Bt,
    const float* __restrict__ bias, const float* __restrict__ R,
    float* __restrict__ Cf, bf16* __restrict__ Cb,
    int N, int K, int act)
{
    __shared__ __align__(16) short As[2][4096];
    __shared__ __align__(16) short Bs[2][4096];
    const int tid  = threadIdx.x;
    const int wave = tid >> 6, lane = tid & 63;
    const int m0 = blockIdx.y * 128;
    const int n0 = blockIdx.x * 128;
    const int lr = lane & 15, lk = lane >> 4;
    const int wm = wave >> 1, wn = wave & 1;

    const bf16* Ab = A  + (size_t)m0 * K;
    const bf16* Bb = Bt + (size_t)n0 * K;

    const int st_row  = (wave * 2) * 16 + (lane >> 2);
    const int st_col0 = (lane & 3);

    f32x4 acc[4][4];
    #pragma unroll
    for (int i = 0; i < 4; ++i)
        #pragma unroll
        for (int j = 0; j < 4; ++j)
            acc[i][j] = (f32x4){0.f, 0.f, 0.f, 0.f};

    const int KT = K >> 5;

    #pragma unroll
    for (int j = 0; j < 2; ++j) {
        int row = st_row + j * 16;
        int ks  = st_col0 ^ (row & 3);
        int chunk = wave * 2 + j;
        async16(Ab + (size_t)row * K + ks * 8, &As[0][chunk * 512]);
        async16(Bb + (size_t)row * K + ks * 8, &Bs[0][chunk * 512]);
    }

    for (int kt = 0; kt < KT; ++kt) {
        const int cur = kt & 1;
        __syncthreads();
        if (kt + 1 < KT) {
            const int k0 = (kt + 1) << 5;
            #pragma unroll
            for (int j = 0; j < 2; ++j) {
                int row = st_row + j * 16;
                int ks  = st_col0 ^ (row & 3);
                int chunk = wave * 2 + j;
                async16(Ab + (size_t)row * K + k0 + ks * 8, &As[cur ^ 1][chunk * 512]);
                async16(Bb + (size_t)row * K + k0 + ks * 8, &Bs[cur ^ 1][chunk * 512]);
            }
        }
        short8 af[4], bfr[4];
        #pragma unroll
        for (int i = 0; i < 4; ++i) {
            int ra = wm * 64 + i * 16 + lr;
            af[i]  = *(const short8*)&As[cur][ra * 32 + ((lk ^ (ra & 3)) << 3)];
            int rb = wn * 64 + i * 16 + lr;
            bfr[i] = *(const short8*)&Bs[cur][rb * 32 + ((lk ^ (rb & 3)) << 3)];
        }
        #pragma unroll
        for (int mi = 0; mi < 4; ++mi)
            #pragma unroll
            for (int ni = 0; ni < 4; ++ni)
                acc[mi][ni] = __builtin_amdgcn_mfma_f32_16x16x32_bf16(af[mi], bfr[ni], acc[mi][ni], 0, 0, 0);
    }

    #pragma unroll
    for (int mi = 0; mi < 4; ++mi) {
        #pragma unroll
        for (int ni = 0; ni < 4; ++ni) {
            int col = n0 + wn * 64 + ni * 16 + lr;
            float bv = bias[col];
            #pragma unroll
            for (int j = 0; j < 4; ++j) {
                int row = m0 + wm * 64 + mi * 16 + lk * 4 + j;
                float t = acc[mi][ni][j] + bv;
                if (act == 1)      t = t / (1.f + __expf(-t));
                else if (act == 2) t = fmaxf(t, 0.f);
                size_t idx = (size_t)row * N + col;
                if (R)  t += R[idx];
                if (Cf) Cf[idx] = t;
                if (Cb) Cb[idx] = __float2bfloat16(t);
            }
        }
    }
}

// ---------------------------------------------------------------- MFMA flash attention
// qkv: (rows,1152)=[q|k|v] bf16. o: (rows,384) bf16. 4 waves, QBLK=64 (16 q-rows/wave).
__global__ __launch_bounds__(256) void attn_mfma(const bf16* __restrict__ qkv,
                                                 bf16* __restrict__ o)
{
    const int qb  = blockIdx.x;      // 0..7 (64 q-rows each)
    const int h   = blockIdx.y;
    const int b   = blockIdx.z;
    const int tid = threadIdx.x;
    const int wave = tid >> 6, lane = tid & 63;
    const int lr = lane & 15, lg = lane >> 4;    // lg in 0..3

    __shared__ __align__(16) short Qs[4096];     // [64 r][64 k] swizzled granules
    __shared__ __align__(16) short Ks[4096];
    __shared__ __align__(16) short Vts[4096];    // transposed: [64 d][64 k] swizzled
    __shared__ __align__(16) short Ps[4][1024];  // per-wave P [16 q][64 k] swizzled

    const size_t baseRow = (size_t)b * S_;
    const bf16* gq = qkv + baseRow * 1152 + (size_t)h * 64;

    // ---- stage Q tile (rows qb*64..+63), XOR-swizzled 16B granules
    #pragma unroll
    for (int i = 0; i < 2; ++i) {
        int cid = i * 256 + tid;                 // 0..511
        int r = cid >> 3, g = cid & 7;
        short8 v = *(const short8*)(gq + (size_t)(qb * 64 + r) * 1152 + g * 8);
        *(short8*)&Qs[r * 64 + ((g ^ (r & 7)) << 3)] = v;
    }

    f32x4 acc_o[4];
    #pragma unroll
    for (int i = 0; i < 4; ++i) acc_o[i] = (f32x4){0.f, 0.f, 0.f, 0.f};
    float m_run[4] = {-1e30f, -1e30f, -1e30f, -1e30f};
    float l_run[4] = {0.f, 0.f, 0.f, 0.f};

    for (int kt = 0; kt < 8; ++kt) {
        __syncthreads();                         // prev-tile compute done (also covers Q stage at kt=0)
        // stage K tile
        #pragma unroll
        for (int i = 0; i < 2; ++i) {
            int cid = i * 256 + tid;
            int r = cid >> 3, g = cid & 7;
            short8 v = *(const short8*)(gq + 384 + (size_t)(kt * 64 + r) * 1152 + g * 8);
            *(short8*)&Ks[r * 64 + ((g ^ (r & 7)) << 3)] = v;
        }
        // stage V transposed: thread (k = tid&63, d0 = (tid>>6)*8 + i*32)
        #pragma unroll
        for (int i = 0; i < 2; ++i) {
            int k  = tid & 63;
            int d0 = ((tid >> 6) << 3) + i * 32;
            short8 v = *(const short8*)(gq + 768 + (size_t)(kt * 64 + k) * 1152 + d0);
            #pragma unroll
            for (int j = 0; j < 8; ++j) {
                int d = d0 + j;
                Vts[d * 64 + (((k >> 3) ^ (d & 7)) << 3) + (k & 7)] = v[j];
            }
        }
        __syncthreads();

        // ---- QK^T: wave's 16 q-rows x 64 k-cols
        f32x4 s[4];
        #pragma unroll
        for (int i = 0; i < 4; ++i) s[i] = (f32x4){0.f, 0.f, 0.f, 0.f};
        short8 qa0, qa1;
        {
            int r = wave * 16 + lr;
            qa0 = *(const short8*)&Qs[r * 64 + ((lg ^ (r & 7)) << 3)];
            qa1 = *(const short8*)&Qs[r * 64 + (((4 + lg) ^ (r & 7)) << 3)];
        }
        #pragma unroll
        for (int ks2 = 0; ks2 < 4; ++ks2) {
            int rk = ks2 * 16 + lr;
            short8 kb0 = *(const short8*)&Ks[rk * 64 + ((lg ^ (rk & 7)) << 3)];
            short8 kb1 = *(const short8*)&Ks[rk * 64 + (((4 + lg) ^ (rk & 7)) << 3)];
            s[ks2] = __builtin_amdgcn_mfma_f32_16x16x32_bf16(qa0, kb0, s[ks2], 0, 0, 0);
            s[ks2] = __builtin_amdgcn_mfma_f32_16x16x32_bf16(qa1, kb1, s[ks2], 0, 0, 0);
        }
        #pragma unroll
        for (int ks2 = 0; ks2 < 4; ++ks2)
            #pragma unroll
            for (int jj = 0; jj < 4; ++jj)
                s[ks2][jj] *= 0.125f;

        // ---- online softmax (row q = (lg*4+jj), spread over 16 lanes)
        #pragma unroll
        for (int jj = 0; jj < 4; ++jj) {
            float tm = fmaxf(fmaxf(s[0][jj], s[1][jj]), fmaxf(s[2][jj], s[3][jj]));
            tm = fmaxf(tm, __shfl_xor(tm, 1));
            tm = fmaxf(tm, __shfl_xor(tm, 2));
            tm = fmaxf(tm, __shfl_xor(tm, 4));
            tm = fmaxf(tm, __shfl_xor(tm, 8));
            float mn = fmaxf(m_run[jj], tm);
            float resc = __expf(m_run[jj] - mn);
            m_run[jj] = mn;
            float rs = 0.f;
            #pragma unroll
            for (int ks2 = 0; ks2 < 4; ++ks2) {
                float p = __expf(s[ks2][jj] - mn);
                s[ks2][jj] = p;
                rs += p;
            }
            rs += __shfl_xor(rs, 1);
            rs += __shfl_xor(rs, 2);
            rs += __shfl_xor(rs, 4);
            rs += __shfl_xor(rs, 8);
            l_run[jj] = l_run[jj] * resc + rs;
            #pragma unroll
            for (int ds2 = 0; ds2 < 4; ++ds2) acc_o[ds2][jj] *= resc;
        }

        // ---- P (C-layout) -> Ps (A-frag layout, wave-private)
        short* pw = &Ps[wave][0];
        #pragma unroll
        for (int ks2 = 0; ks2 < 4; ++ks2)
            #pragma unroll
            for (int jj = 0; jj < 4; ++jj) {
                int q = lg * 4 + jj;
                int k = ks2 * 16 + lr;
                bf16 pb = __float2bfloat16(s[ks2][jj]);
                pw[q * 64 + (((k >> 3) ^ (q & 7)) << 3) + (k & 7)] = *(short*)&pb;
            }
        short8 pa0 = *(const short8*)&pw[lr * 64 + ((lg ^ (lr & 7)) << 3)];
        short8 pa1 = *(const short8*)&pw[lr * 64 + (((4 + lg) ^ (lr & 7)) << 3)];

        // ---- PV: O[16 q][64 d] += P @ V
        #pragma unroll
        for (int ds2 = 0; ds2 < 4; ++ds2) {
            int d = ds2 * 16 + lr;
            short8 vb0 = *(const short8*)&Vts[d * 64 + ((lg ^ (d & 7)) << 3)];
            short8 vb1 = *(const short8*)&Vts[d * 64 + (((4 + lg) ^ (d & 7)) << 3)];
            acc_o[ds2] = __builtin_amdgcn_mfma_f32_16x16x32_bf16(pa0, vb0, acc_o[ds2], 0, 0, 0);
            acc_o[ds2] = __builtin_amdgcn_mfma_f32_16x16x32_bf16(pa1, vb1, acc_o[ds2], 0, 0, 0);
        }
    }

    // ---- epilogue: O /= l, write bf16
    #pragma unroll
    for (int jj = 0; jj < 4; ++jj) {
        float inv = 1.f / l_run[jj];
        size_t row = baseRow + qb * 64 + wave * 16 + lg * 4 + jj;
        #pragma unroll
        for (int ds2 = 0; ds2 < 4; ++ds2)
            o[row * 384 + h * 64 + ds2 * 16 + lr] = __float2bfloat16(acc_o[ds2][jj] * inv);
    }
}

// ---------------------------------------------------------------- classifier head
__global__ __launch_bounds__(128) void head_kernel(const float* __restrict__ cls,
    const float* __restrict__ w1, const float* __restrict__ b1,
    const float* __restrict__ w2, const float* __restrict__ b2,
    float* __restrict__ out)
{
    int b = blockIdx.x;
    int tid = threadIdx.x;
    __shared__ float c[384];
    const float* xr = cls + (size_t)b * 384;
    for (int d = tid; d < 384; d += 128) c[d] = xr[d];
    __syncthreads();
    float hacc = b1[tid];
    for (int k = 0; k < 384; ++k) hacc += c[k] * w1[k * 128 + tid];
    hacc = fmaxf(hacc, 0.f);
    float p = hacc * w2[tid];
    #pragma unroll
    for (int off = 32; off > 0; off >>= 1) p += __shfl_down(p, off);
    __shared__ float r2[2];
    if ((tid & 63) == 0) r2[tid >> 6] = p;
    __syncthreads();
    if (tid == 0) out[b] = r2[0] + r2[1] + b2[0];
}

// ---------------------------------------------------------------- launch
extern "C" void kernel_launch(void* const* d_in, const int* in_sizes, int n_in,
                              void* d_out, int out_size, void* d_ws, size_t ws_size,
                              hipStream_t stream)
{
    const int*   ids     = (const int*)d_in[0];
    const float* emb     = (const float*)d_in[1];
    const float* pos     = (const float*)d_in[2];
    const float* m_ln_w  = (const float*)d_in[3];
    const float* m_ln_b  = (const float*)d_in[4];
    const float* m_W1    = (const float*)d_in[5];
    const float* m_b1    = (const float*)d_in[6];
    const float* m_W2    = (const float*)d_in[7];
    const float* m_b2    = (const float*)d_in[8];
    const float* a_qkv_w = (const float*)d_in[9];
    const float* a_qkv_b = (const float*)d_in[10];
    const float* a_out_w = (const float*)d_in[11];
    const float* a_out_b = (const float*)d_in[12];
    const float* a_ln1_w = (const float*)d_in[13];
    const float* a_ln1_b = (const float*)d_in[14];
    const float* a_ln2_w = (const float*)d_in[15];
    const float* a_ln2_b = (const float*)d_in[16];
    const float* a_ff_w1 = (const float*)d_in[17];
    const float* a_ff_b1 = (const float*)d_in[18];
    const float* a_ff_w2 = (const float*)d_in[19];
    const float* a_ff_b2 = (const float*)d_in[20];
    const float* fn_w    = (const float*)d_in[21];
    const float* fn_b    = (const float*)d_in[22];
    const float* h_w1    = (const float*)d_in[23];
    const float* h_b1    = (const float*)d_in[24];
    const float* h_w2    = (const float*)d_in[25];
    const float* h_b2    = (const float*)d_in[26];
    float* out = (float*)d_out;

    const size_t M = (size_t)B_ * S_;      // 65536
    const size_t WBYTES = 7077888ull * 2;  // transposed bf16 weights: 14.16 MB

    // adaptive chunk count: smallest NC whose buffers fit ws_size
    // need = x(fp32, M*1536B) + MC*6144B (t0 fp32 + xcb + midb + t2b bf16) + weights
    int NC = 8;
    {
        const int cand[4] = {1, 2, 4, 8};
        for (int ci = 0; ci < 4; ++ci) {
            size_t mc = M / cand[ci];
            size_t need = M * 1536 + mc * 6144 + WBYTES + 1024;
            if (need <= ws_size) { NC = cand[ci]; break; }
        }
    }
    const size_t MC = M / NC;
    const int    BC = (int)(MC / S_);

    char* wp = (char*)d_ws;
    float* x    = (float*)wp;               wp += M  * 384 * 4;
    float* t0   = (float*)wp;               wp += MC * 384 * 4;
    bf16*  xcb  = (bf16*)wp;                wp += MC * 384 * 2;
    bf16*  midb = (bf16*)wp;                wp += MC * 1536 * 2;
    bf16*  t2b  = (bf16*)wp;                wp += MC * 384 * 2;
    bf16*  Wt   = (bf16*)wp;

    bf16* mW1t = Wt;
    bf16* mW2t = mW1t + 6 * 768 * 384;
    bf16* qkvt = mW2t + 6 * 384 * 768;
    bf16* outt = qkvt + 2 * 1152 * 384;
    bf16* ff1t = outt + 2 * 384 * 384;
    bf16* ff2t = ff1t + 2 * 1536 * 384;

    for (int i = 0; i < NM_; ++i) {
        wcvt_kernel<<<dim3(DIN_ / 32, D_ / 32), 256, 0, stream>>>(m_W1 + (size_t)i * D_ * DIN_, mW1t + (size_t)i * DIN_ * D_, D_, DIN_);
        wcvt_kernel<<<dim3(D_ / 32, DIN_ / 32), 256, 0, stream>>>(m_W2 + (size_t)i * DIN_ * D_, mW2t + (size_t)i * D_ * DIN_, DIN_, D_);
    }
    for (int i = 0; i < NA_; ++i) {
        wcvt_kernel<<<dim3(1152 / 32, D_ / 32), 256, 0, stream>>>(a_qkv_w + (size_t)i * D_ * 1152, qkvt + (size_t)i * 1152 * D_, D_, 1152);
        wcvt_kernel<<<dim3(D_ / 32, D_ / 32), 256, 0, stream>>>(a_out_w + (size_t)i * D_ * D_, outt + (size_t)i * D_ * D_, D_, D_);
        wcvt_kernel<<<dim3(DFF_ / 32, D_ / 32), 256, 0, stream>>>(a_ff_w1 + (size_t)i * D_ * DFF_, ff1t + (size_t)i * DFF_ * D_, D_, DFF_);
        wcvt_kernel<<<dim3(D_ / 32, DFF_ / 32), 256, 0, stream>>>(a_ff_w2 + (size_t)i * DFF_ * D_, ff2t + (size_t)i * D_ * DFF_, DFF_, D_);
    }

    embed_kernel<<<(int)M, 128, 0, stream>>>(ids, emb, pos, x);

    const int GM = (int)(MC / 128);

    for (int i = 0; i < NM_; ++i) {
        for (int c = 0; c < NC; ++c) {
            float* xc = x + (size_t)c * MC * 384;
            ln_kernel<<<(int)MC, 128, 0, stream>>>(xc, nullptr, m_ln_w + i * D_, m_ln_b + i * D_, nullptr, xcb);
            gemm_bf16<<<dim3(DIN_ / 128, GM), 256, 0, stream>>>(
                xcb, mW1t + (size_t)i * DIN_ * D_, m_b1 + i * DIN_, nullptr, nullptr, midb, DIN_, D_, 1);
            gemm_bf16<<<dim3(D_ / 128, GM), 256, 0, stream>>>(
                midb, mW2t + (size_t)i * D_ * DIN_, m_b2 + i * D_, xc, xc, nullptr, D_, DIN_, 0);
        }
    }
    for (int i = 0; i < NA_; ++i) {
        for (int c = 0; c < NC; ++c) {
            float* xc = x + (size_t)c * MC * 384;
            cvt_kernel<<<(int)(MC * 384 / 1024), 256, 0, stream>>>(xc, xcb);
            gemm_bf16<<<dim3(1152 / 128, GM), 256, 0, stream>>>(
                xcb, qkvt + (size_t)i * 1152 * D_, a_qkv_b + i * 1152, nullptr, nullptr, midb, 1152, D_, 0);
            attn_mfma<<<dim3(S_ / 64, H_, BC), 256, 0, stream>>>(midb, t2b);
            gemm_bf16<<<dim3(D_ / 128, GM), 256, 0, stream>>>(
                t2b, outt + (size_t)i * D_ * D_, a_out_b + i * D_, nullptr, t0, nullptr, D_, D_, 0);
            ln_kernel<<<(int)MC, 128, 0, stream>>>(xc, t0, a_ln1_w + i * D_, a_ln1_b + i * D_, xc, xcb);
            gemm_bf16<<<dim3(DFF_ / 128, GM), 256, 0, stream>>>(
                xcb, ff1t + (size_t)i * DFF_ * D_, a_ff_b1 + i * DFF_, nullptr, nullptr, midb, DFF_, D_, 2);
            gemm_bf16<<<dim3(D_ / 128, GM), 256, 0, stream>>>(
                midb, ff2t + (size_t)i * D_ * DFF_, a_ff_b2 + i * D_, nullptr, t0, nullptr, D_, DFF_, 0);
            ln_kernel<<<(int)MC, 128, 0, stream>>>(xc, t0, a_ln2_w + i * D_, a_ln2_b + i * D_, xc, nullptr);
        }
    }
    ln_cls_kernel<<<B_, 128, 0, stream>>>(x, fn_w, fn_b, t0);
    head_kernel<<<B_, 128, 0, stream>>>(t0, h_w1, h_b1, h_w2, h_b2, out);
}

// Round 10
// 3978.167 us; speedup vs baseline: 5.8917x; 1.0243x over previous
//
#include <hip/hip_runtime.h>
#include <hip/hip_bf16.h>
#include <math.h>

#define B_   128
#define S_   512
#define D_   384
#define H_   6
#define HD_  64
#define DIN_ 768
#define DFF_ 1536
#define NM_  6
#define NA_  2
#define EPS_ 1e-5f

typedef __hip_bfloat16 bf16;
typedef __attribute__((ext_vector_type(8))) short short8;
typedef __attribute__((ext_vector_type(4))) float f32x4;

__device__ __forceinline__ float bf2f(unsigned short u) {
    union { unsigned int i; float f; } c; c.i = ((unsigned int)u) << 16; return c.f;
}

__device__ __forceinline__ void async16(const void* g, void* l) {
    __builtin_amdgcn_global_load_lds((const __attribute__((address_space(1))) void*)g,
                                     (__attribute__((address_space(3))) void*)l, 16, 0, 0);
}

// ---------------------------------------------------------------- embed (fp32 out)
__global__ __launch_bounds__(128) void embed_kernel(const int* __restrict__ ids,
    const float* __restrict__ emb, const float* __restrict__ pos,
    float* __restrict__ x)
{
    int row = blockIdx.x;
    int id  = ids[row];
    int s   = row & (S_ - 1);
    const float* e = emb + (size_t)id * D_;
    const float* p = pos + (size_t)s * D_;
    float* xr = x + (size_t)row * D_;
    for (int d = threadIdx.x; d < D_; d += 128) xr[d] = e[d] + p[d];
}

// ---------------------------------------------------------------- layernorm: optional bf16 residual, dual dtype out
__global__ __launch_bounds__(128) void ln_kernel(const float* __restrict__ src,
    const bf16* __restrict__ res, const float* __restrict__ w,
    const float* __restrict__ bias, float* __restrict__ outf, bf16* __restrict__ outb)
{
    int row = blockIdx.x;
    const float* sr = src + (size_t)row * D_;
    int tid = threadIdx.x;
    float v[3];
    float s = 0.f, ss = 0.f;
    #pragma unroll
    for (int i = 0; i < 3; ++i) {
        int d = tid + i * 128;
        float t = sr[d];
        if (res) t += __bfloat162float(res[(size_t)row * D_ + d]);
        v[i] = t; s += t; ss += t * t;
    }
    #pragma unroll
    for (int off = 32; off > 0; off >>= 1) {
        s  += __shfl_down(s, off);
        ss += __shfl_down(ss, off);
    }
    __shared__ float red[2][2];
    int wave = tid >> 6, lane = tid & 63;
    if (lane == 0) { red[wave][0] = s; red[wave][1] = ss; }
    __syncthreads();
    float S0 = red[0][0] + red[1][0];
    float SS = red[0][1] + red[1][1];
    float mu  = S0 * (1.f / D_);
    float var = SS * (1.f / D_) - mu * mu;
    float rs  = rsqrtf(var + EPS_);
    #pragma unroll
    for (int i = 0; i < 3; ++i) {
        int d = tid + i * 128;
        float o = (v[i] - mu) * rs * w[d] + bias[d];
        if (outf) outf[(size_t)row * D_ + d] = o;
        if (outb) outb[(size_t)row * D_ + d] = __float2bfloat16(o);
    }
}

// ---------------------------------------------------------------- final LN on CLS rows only
__global__ __launch_bounds__(128) void ln_cls_kernel(const float* __restrict__ x,
    const float* __restrict__ w, const float* __restrict__ bias, float* __restrict__ cls)
{
    int b = blockIdx.x;
    const float* sr = x + (size_t)b * S_ * D_;
    int tid = threadIdx.x;
    float v[3];
    float s = 0.f, ss = 0.f;
    #pragma unroll
    for (int i = 0; i < 3; ++i) {
        int d = tid + i * 128;
        float t = sr[d];
        v[i] = t; s += t; ss += t * t;
    }
    #pragma unroll
    for (int off = 32; off > 0; off >>= 1) {
        s  += __shfl_down(s, off);
        ss += __shfl_down(ss, off);
    }
    __shared__ float red[2][2];
    int wave = tid >> 6, lane = tid & 63;
    if (lane == 0) { red[wave][0] = s; red[wave][1] = ss; }
    __syncthreads();
    float S0 = red[0][0] + red[1][0];
    float SS = red[0][1] + red[1][1];
    float mu  = S0 * (1.f / D_);
    float var = SS * (1.f / D_) - mu * mu;
    float rs  = rsqrtf(var + EPS_);
    #pragma unroll
    for (int i = 0; i < 3; ++i) {
        int d = tid + i * 128;
        cls[(size_t)b * D_ + d] = (v[i] - mu) * rs * w[d] + bias[d];
    }
}

// ---------------------------------------------------------------- weight transpose+cvt (batched over layer via blockIdx.z)
// src W: (K x N fp32), dst Wt: (N x K bf16)
__global__ __launch_bounds__(256) void wcvt_kernel(const float* __restrict__ W,
    bf16* __restrict__ Wt, int K, int N)
{
    W  += (size_t)blockIdx.z * K * N;
    Wt += (size_t)blockIdx.z * N * K;
    __shared__ float tile[32][33];
    int tid = threadIdx.x;
    int tx = tid & 31, ty = tid >> 5;
    int n0 = blockIdx.x * 32, k0 = blockIdx.y * 32;
    #pragma unroll
    for (int i = 0; i < 4; ++i)
        tile[ty + i * 8][tx] = W[(size_t)(k0 + ty + i * 8) * N + n0 + tx];
    __syncthreads();
    #pragma unroll
    for (int i = 0; i < 4; ++i)
        Wt[(size_t)(n0 + ty + i * 8) * K + k0 + tx] = __float2bfloat16(tile[tx][ty + i * 8]);
}

// ---------------------------------------------------------------- bf16 MFMA GEMM
// A: McxK bf16 row-major.  Bt: NxK bf16 row-major (= W^T).  C = act(A@W + bias) [+R]
__global__ __launch_bounds__(256) void gemm_bf16(
    const bf16* __restrict__ A, const bf16* __restrict__ Bt,
    const float* __restrict__ bias, const float* __restrict__ R,
    float* __restrict__ Cf, bf16* __restrict__ Cb,
    int N, int K, int act)
{
    __shared__ __align__(16) short As[2][4096];
    __shared__ __align__(16) short Bs[2][4096];
    const int tid  = threadIdx.x;
    const int wave = tid >> 6, lane = tid & 63;
    const int m0 = blockIdx.y * 128;
    const int n0 = blockIdx.x * 128;
    const int lr = lane & 15, lk = lane >> 4;
    const int wm = wave >> 1, wn = wave & 1;

    const bf16* Ab = A  + (size_t)m0 * K;
    const bf16* Bb = Bt + (size_t)n0 * K;

    const int st_row  = (wave * 2) * 16 + (lane >> 2);
    const int st_col0 = (lane & 3);

    f32x4 acc[4][4];
    #pragma unroll
    for (int i = 0; i < 4; ++i)
        #pragma unroll
        for (int j = 0; j < 4; ++j)
            acc[i][j] = (f32x4){0.f, 0.f, 0.f, 0.f};

    const int KT = K >> 5;

    #pragma unroll
    for (int j = 0; j < 2; ++j) {
        int row = st_row + j * 16;
        int ks  = st_col0 ^ (row & 3);
        int chunk = wave * 2 + j;
        async16(Ab + (size_t)row * K + ks * 8, &As[0][chunk * 512]);
        async16(Bb + (size_t)row * K + ks * 8, &Bs[0][chunk * 512]);
    }

    for (int kt = 0; kt < KT; ++kt) {
        const int cur = kt & 1;
        __syncthreads();
        if (kt + 1 < KT) {
            const int k0 = (kt + 1) << 5;
            #pragma unroll
            for (int j = 0; j < 2; ++j) {
                int row = st_row + j * 16;
                int ks  = st_col0 ^ (row & 3);
                int chunk = wave * 2 + j;
                async16(Ab + (size_t)row * K + k0 + ks * 8, &As[cur ^ 1][chunk * 512]);
                async16(Bb + (size_t)row * K + k0 + ks * 8, &Bs[cur ^ 1][chunk * 512]);
            }
        }
        short8 af[4], bfr[4];
        #pragma unroll
        for (int i = 0; i < 4; ++i) {
            int ra = wm * 64 + i * 16 + lr;
            af[i]  = *(const short8*)&As[cur][ra * 32 + ((lk ^ (ra & 3)) << 3)];
            int rb = wn * 64 + i * 16 + lr;
            bfr[i] = *(const short8*)&Bs[cur][rb * 32 + ((lk ^ (rb & 3)) << 3)];
        }
        #pragma unroll
        for (int mi = 0; mi < 4; ++mi)
            #pragma unroll
            for (int ni = 0; ni < 4; ++ni)
                acc[mi][ni] = __builtin_amdgcn_mfma_f32_16x16x32_bf16(af[mi], bfr[ni], acc[mi][ni], 0, 0, 0);
    }

    #pragma unroll
    for (int mi = 0; mi < 4; ++mi) {
        #pragma unroll
        for (int ni = 0; ni < 4; ++ni) {
            int col = n0 + wn * 64 + ni * 16 + lr;
            float bv = bias[col];
            #pragma unroll
            for (int j = 0; j < 4; ++j) {
                int row = m0 + wm * 64 + mi * 16 + lk * 4 + j;
                float t = acc[mi][ni][j] + bv;
                if (act == 1)      t = t / (1.f + __expf(-t));
                else if (act == 2) t = fmaxf(t, 0.f);
                size_t idx = (size_t)row * N + col;
                if (R)  t += R[idx];
                if (Cf) Cf[idx] = t;
                if (Cb) Cb[idx] = __float2bfloat16(t);
            }
        }
    }
}

// ---------------------------------------------------------------- MFMA flash attention
// qkv: (rows,1152)=[q|k|v] bf16. o: (rows,384) bf16. 4 waves, QBLK=64 (16 q-rows/wave).
__global__ __launch_bounds__(256) void attn_mfma(const bf16* __restrict__ qkv,
                                                 bf16* __restrict__ o)
{
    const int qb  = blockIdx.x;
    const int h   = blockIdx.y;
    const int b   = blockIdx.z;
    const int tid = threadIdx.x;
    const int wave = tid >> 6, lane = tid & 63;
    const int lr = lane & 15, lg = lane >> 4;

    __shared__ __align__(16) short Qs[4096];
    __shared__ __align__(16) short Ks[4096];
    __shared__ __align__(16) short Vts[4096];
    __shared__ __align__(16) short Ps[4][1024];

    const size_t baseRow = (size_t)b * S_;
    const bf16* gq = qkv + baseRow * 1152 + (size_t)h * 64;

    #pragma unroll
    for (int i = 0; i < 2; ++i) {
        int cid = i * 256 + tid;
        int r = cid >> 3, g = cid & 7;
        short8 v = *(const short8*)(gq + (size_t)(qb * 64 + r) * 1152 + g * 8);
        *(short8*)&Qs[r * 64 + ((g ^ (r & 7)) << 3)] = v;
    }

    f32x4 acc_o[4];
    #pragma unroll
    for (int i = 0; i < 4; ++i) acc_o[i] = (f32x4){0.f, 0.f, 0.f, 0.f};
    float m_run[4] = {-1e30f, -1e30f, -1e30f, -1e30f};
    float l_run[4] = {0.f, 0.f, 0.f, 0.f};

    for (int kt = 0; kt < 8; ++kt) {
        __syncthreads();
        #pragma unroll
        for (int i = 0; i < 2; ++i) {
            int cid = i * 256 + tid;
            int r = cid >> 3, g = cid & 7;
            short8 v = *(const short8*)(gq + 384 + (size_t)(kt * 64 + r) * 1152 + g * 8);
            *(short8*)&Ks[r * 64 + ((g ^ (r & 7)) << 3)] = v;
        }
        #pragma unroll
        for (int i = 0; i < 2; ++i) {
            int k  = tid & 63;
            int d0 = ((tid >> 6) << 3) + i * 32;
            short8 v = *(const short8*)(gq + 768 + (size_t)(kt * 64 + k) * 1152 + d0);
            #pragma unroll
            for (int j = 0; j < 8; ++j) {
                int d = d0 + j;
                Vts[d * 64 + (((k >> 3) ^ (d & 7)) << 3) + (k & 7)] = v[j];
            }
        }
        __syncthreads();

        f32x4 s[4];
        #pragma unroll
        for (int i = 0; i < 4; ++i) s[i] = (f32x4){0.f, 0.f, 0.f, 0.f};
        short8 qa0, qa1;
        {
            int r = wave * 16 + lr;
            qa0 = *(const short8*)&Qs[r * 64 + ((lg ^ (r & 7)) << 3)];
            qa1 = *(const short8*)&Qs[r * 64 + (((4 + lg) ^ (r & 7)) << 3)];
        }
        #pragma unroll
        for (int ks2 = 0; ks2 < 4; ++ks2) {
            int rk = ks2 * 16 + lr;
            short8 kb0 = *(const short8*)&Ks[rk * 64 + ((lg ^ (rk & 7)) << 3)];
            short8 kb1 = *(const short8*)&Ks[rk * 64 + (((4 + lg) ^ (rk & 7)) << 3)];
            s[ks2] = __builtin_amdgcn_mfma_f32_16x16x32_bf16(qa0, kb0, s[ks2], 0, 0, 0);
            s[ks2] = __builtin_amdgcn_mfma_f32_16x16x32_bf16(qa1, kb1, s[ks2], 0, 0, 0);
        }
        #pragma unroll
        for (int ks2 = 0; ks2 < 4; ++ks2)
            #pragma unroll
            for (int jj = 0; jj < 4; ++jj)
                s[ks2][jj] *= 0.125f;

        #pragma unroll
        for (int jj = 0; jj < 4; ++jj) {
            float tm = fmaxf(fmaxf(s[0][jj], s[1][jj]), fmaxf(s[2][jj], s[3][jj]));
            tm = fmaxf(tm, __shfl_xor(tm, 1));
            tm = fmaxf(tm, __shfl_xor(tm, 2));
            tm = fmaxf(tm, __shfl_xor(tm, 4));
            tm = fmaxf(tm, __shfl_xor(tm, 8));
            float mn = fmaxf(m_run[jj], tm);
            float resc = __expf(m_run[jj] - mn);
            m_run[jj] = mn;
            float rs = 0.f;
            #pragma unroll
            for (int ks2 = 0; ks2 < 4; ++ks2) {
                float p = __expf(s[ks2][jj] - mn);
                s[ks2][jj] = p;
                rs += p;
            }
            rs += __shfl_xor(rs, 1);
            rs += __shfl_xor(rs, 2);
            rs += __shfl_xor(rs, 4);
            rs += __shfl_xor(rs, 8);
            l_run[jj] = l_run[jj] * resc + rs;
            #pragma unroll
            for (int ds2 = 0; ds2 < 4; ++ds2) acc_o[ds2][jj] *= resc;
        }

        short* pw = &Ps[wave][0];
        #pragma unroll
        for (int ks2 = 0; ks2 < 4; ++ks2)
            #pragma unroll
            for (int jj = 0; jj < 4; ++jj) {
                int q = lg * 4 + jj;
                int k = ks2 * 16 + lr;
                bf16 pb = __float2bfloat16(s[ks2][jj]);
                pw[q * 64 + (((k >> 3) ^ (q & 7)) << 3) + (k & 7)] = *(short*)&pb;
            }
        short8 pa0 = *(const short8*)&pw[lr * 64 + ((lg ^ (lr & 7)) << 3)];
        short8 pa1 = *(const short8*)&pw[lr * 64 + (((4 + lg) ^ (lr & 7)) << 3)];

        #pragma unroll
        for (int ds2 = 0; ds2 < 4; ++ds2) {
            int d = ds2 * 16 + lr;
            short8 vb0 = *(const short8*)&Vts[d * 64 + ((lg ^ (d & 7)) << 3)];
            short8 vb1 = *(const short8*)&Vts[d * 64 + (((4 + lg) ^ (d & 7)) << 3)];
            acc_o[ds2] = __builtin_amdgcn_mfma_f32_16x16x32_bf16(pa0, vb0, acc_o[ds2], 0, 0, 0);
            acc_o[ds2] = __builtin_amdgcn_mfma_f32_16x16x32_bf16(pa1, vb1, acc_o[ds2], 0, 0, 0);
        }
    }

    #pragma unroll
    for (int jj = 0; jj < 4; ++jj) {
        float inv = 1.f / l_run[jj];
        size_t row = baseRow + qb * 64 + wave * 16 + lg * 4 + jj;
        #pragma unroll
        for (int ds2 = 0; ds2 < 4; ++ds2)
            o[row * 384 + h * 64 + ds2 * 16 + lr] = __float2bfloat16(acc_o[ds2][jj] * inv);
    }
}

// ---------------------------------------------------------------- classifier head
__global__ __launch_bounds__(128) void head_kernel(const float* __restrict__ cls,
    const float* __restrict__ w1, const float* __restrict__ b1,
    const float* __restrict__ w2, const float* __restrict__ b2,
    float* __restrict__ out)
{
    int b = blockIdx.x;
    int tid = threadIdx.x;
    __shared__ float c[384];
    const float* xr = cls + (size_t)b * 384;
    for (int d = tid; d < 384; d += 128) c[d] = xr[d];
    __syncthreads();
    float hacc = b1[tid];
    for (int k = 0; k < 384; ++k) hacc += c[k] * w1[k * 128 + tid];
    hacc = fmaxf(hacc, 0.f);
    float p = hacc * w2[tid];
    #pragma unroll
    for (int off = 32; off > 0; off >>= 1) p += __shfl_down(p, off);
    __shared__ float r2[2];
    if ((tid & 63) == 0) r2[tid >> 6] = p;
    __syncthreads();
    if (tid == 0) out[b] = r2[0] + r2[1] + b2[0];
}

// ---------------------------------------------------------------- launch
// Workspace layout:
//   x    : M*384 fp32   residual stream (100.7 MB)   persistent
//   xb   : M*384 bf16   bf16 mirror for qkv input (50.3 MB)  persistent
//   xcb  : MC*384 bf16  LN output -> GEMM A
//   midb : MC*1536 bf16 W1 mid / qkv / FF mid; attn-out aliases midb+MC*1152
//   t0b  : MC*384 bf16  pre-residual branch outputs (outproj / ff2)
//   Wt   : 14.2 MB bf16 transposed weights
// need(NC) = 165.2 MB + MC*4608 B   ->  NC=1: 467 MB, NC=2: 316 MB, NC=4: 241 MB, NC=8: 203 MB
extern "C" void kernel_launch(void* const* d_in, const int* in_sizes, int n_in,
                              void* d_out, int out_size, void* d_ws, size_t ws_size,
                              hipStream_t stream)
{
    const int*   ids     = (const int*)d_in[0];
    const float* emb     = (const float*)d_in[1];
    const float* pos     = (const float*)d_in[2];
    const float* m_ln_w  = (const float*)d_in[3];
    const float* m_ln_b  = (const float*)d_in[4];
    const float* m_W1    = (const float*)d_in[5];
    const float* m_b1    = (const float*)d_in[6];
    const float* m_W2    = (const float*)d_in[7];
    const float* m_b2    = (const float*)d_in[8];
    const float* a_qkv_w = (const float*)d_in[9];
    const float* a_qkv_b = (const float*)d_in[10];
    const float* a_out_w = (const float*)d_in[11];
    const float* a_out_b = (const float*)d_in[12];
    const float* a_ln1_w = (const float*)d_in[13];
    const float* a_ln1_b = (const float*)d_in[14];
    const float* a_ln2_w = (const float*)d_in[15];
    const float* a_ln2_b = (const float*)d_in[16];
    const float* a_ff_w1 = (const float*)d_in[17];
    const float* a_ff_b1 = (const float*)d_in[18];
    const float* a_ff_w2 = (const float*)d_in[19];
    const float* a_ff_b2 = (const float*)d_in[20];
    const float* fn_w    = (const float*)d_in[21];
    const float* fn_b    = (const float*)d_in[22];
    const float* h_w1    = (const float*)d_in[23];
    const float* h_b1    = (const float*)d_in[24];
    const float* h_w2    = (const float*)d_in[25];
    const float* h_b2    = (const float*)d_in[26];
    float* out = (float*)d_out;

    const size_t M = (size_t)B_ * S_;        // 65536
    const size_t WBYTES = 7077888ull * 2;    // 14.16 MB

    int NC = 8;
    {
        const int cand[4] = {1, 2, 4, 8};
        for (int ci = 0; ci < 4; ++ci) {
            size_t mc = M / cand[ci];
            size_t need = M * 1536 + M * 768 + mc * 4608 + WBYTES + 4096;
            if (need <= ws_size) { NC = cand[ci]; break; }
        }
    }
    const size_t MC = M / NC;
    const int    BC = (int)(MC / S_);

    char* wp = (char*)d_ws;
    float* x    = (float*)wp;               wp += M  * 384 * 4;
    bf16*  xb   = (bf16*)wp;                wp += M  * 384 * 2;
    bf16*  xcb  = (bf16*)wp;                wp += MC * 384 * 2;
    bf16*  midb = (bf16*)wp;                wp += MC * 1536 * 2;
    bf16*  t0b  = (bf16*)wp;                wp += MC * 384 * 2;
    bf16*  Wt   = (bf16*)wp;
    bf16*  t2b  = midb + MC * 1152;         // alias: attn out lives in midb tail

    bf16* mW1t = Wt;
    bf16* mW2t = mW1t + 6 * 768 * 384;
    bf16* qkvt = mW2t + 6 * 384 * 768;
    bf16* outt = qkvt + 2 * 1152 * 384;
    bf16* ff1t = outt + 2 * 384 * 384;
    bf16* ff2t = ff1t + 2 * 1536 * 384;

    // ---- weight conversion: 6 batched launches
    wcvt_kernel<<<dim3(DIN_ / 32, D_ / 32, NM_), 256, 0, stream>>>(m_W1, mW1t, D_, DIN_);
    wcvt_kernel<<<dim3(D_ / 32, DIN_ / 32, NM_), 256, 0, stream>>>(m_W2, mW2t, DIN_, D_);
    wcvt_kernel<<<dim3(1152 / 32, D_ / 32, NA_), 256, 0, stream>>>(a_qkv_w, qkvt, D_, 1152);
    wcvt_kernel<<<dim3(D_ / 32, D_ / 32, NA_), 256, 0, stream>>>(a_out_w, outt, D_, D_);
    wcvt_kernel<<<dim3(DFF_ / 32, D_ / 32, NA_), 256, 0, stream>>>(a_ff_w1, ff1t, D_, DFF_);
    wcvt_kernel<<<dim3(D_ / 32, DFF_ / 32, NA_), 256, 0, stream>>>(a_ff_w2, ff2t, DFF_, D_);

    embed_kernel<<<(int)M, 128, 0, stream>>>(ids, emb, pos, x);

    const int GM = (int)(MC / 128);

    for (int i = 0; i < NM_; ++i) {
        for (int c = 0; c < NC; ++c) {
            float* xc  = x  + (size_t)c * MC * 384;
            bf16*  xbc = xb + (size_t)c * MC * 384;
            ln_kernel<<<(int)MC, 128, 0, stream>>>(xc, nullptr, m_ln_w + i * D_, m_ln_b + i * D_, nullptr, xcb);
            gemm_bf16<<<dim3(DIN_ / 128, GM), 256, 0, stream>>>(
                xcb, mW1t + (size_t)i * DIN_ * D_, m_b1 + i * DIN_, nullptr, nullptr, midb, DIN_, D_, 1);
            // last MLP block dual-writes the bf16 mirror consumed by attn qkv
            gemm_bf16<<<dim3(D_ / 128, GM), 256, 0, stream>>>(
                midb, mW2t + (size_t)i * D_ * DIN_, m_b2 + i * D_, xc, xc,
                (i == NM_ - 1) ? xbc : nullptr, D_, DIN_, 0);
        }
    }
    for (int i = 0; i < NA_; ++i) {
        for (int c = 0; c < NC; ++c) {
            float* xc  = x  + (size_t)c * MC * 384;
            bf16*  xbc = xb + (size_t)c * MC * 384;
            gemm_bf16<<<dim3(1152 / 128, GM), 256, 0, stream>>>(
                xbc, qkvt + (size_t)i * 1152 * D_, a_qkv_b + i * 1152, nullptr, nullptr, midb, 1152, D_, 0);
            attn_mfma<<<dim3(S_ / 64, H_, BC), 256, 0, stream>>>(midb, t2b);
            gemm_bf16<<<dim3(D_ / 128, GM), 256, 0, stream>>>(
                t2b, outt + (size_t)i * D_ * D_, a_out_b + i * D_, nullptr, nullptr, t0b, D_, D_, 0);
            ln_kernel<<<(int)MC, 128, 0, stream>>>(xc, t0b, a_ln1_w + i * D_, a_ln1_b + i * D_, xc, xcb);
            gemm_bf16<<<dim3(DFF_ / 128, GM), 256, 0, stream>>>(
                xcb, ff1t + (size_t)i * DFF_ * D_, a_ff_b1 + i * DFF_, nullptr, nullptr, midb, DFF_, D_, 2);
            gemm_bf16<<<dim3(D_ / 128, GM), 256, 0, stream>>>(
                midb, ff2t + (size_t)i * D_ * DFF_, a_ff_b2 + i * D_, nullptr, nullptr, t0b, D_, DFF_, 0);
            // ln2: write fp32 stream always; write bf16 mirror only if a next attn block consumes it
            ln_kernel<<<(int)MC, 128, 0, stream>>>(xc, t0b, a_ln2_w + i * D_, a_ln2_b + i * D_, xc,
                                                   (i + 1 < NA_) ? xbc : nullptr);
        }
    }
    ln_cls_kernel<<<B_, 128, 0, stream>>>(x, fn_w, fn_b, (float*)((char*)d_ws + M * 384 * 4 + M * 384 * 2));
    // reuse xcb region start as fp32 cls scratch (128*384 floats = 192KB, fits in xcb's 50MB)
    head_kernel<<<B_, 128, 0, stream>>>((const float*)((char*)d_ws + M * 384 * 4 + M * 384 * 2),
                                        h_w1, h_b1, h_w2, h_b2, out);
}